// Round 6
// baseline (1630.459 us; speedup 1.0000x reference)
//
#include <hip/hip_runtime.h>
#include <math.h>

#define DIM 192
#define HEADS 6
#define HD 32
#define WS 7
#define NN 49
#define NWIN 4096
#define QKV_ROW (3*DIM)

typedef __attribute__((ext_vector_type(8))) short bf16x8_t;
typedef __attribute__((ext_vector_type(4))) float f32x4_t;

#define MFMA16(a,b,c) __builtin_amdgcn_mfma_f32_16x16x32_bf16((a),(b),(c),0,0,0)

__device__ __forceinline__ float gelu_tanh(float x) {
    const float k0 = 0.7978845608028654f; // sqrt(2/pi)
    const float k1 = 0.044715f;
    float t = tanhf(k0 * (x + k1 * x * x * x));
    return 0.5f * x * (1.0f + t);
}
__device__ __forceinline__ unsigned short f2bf(float f) {
    __bf16 h = (__bf16)f;
    return __builtin_bit_cast(unsigned short, h);
}
__device__ __forceinline__ float bf2f(unsigned short u) {
    return (float)__builtin_bit_cast(__bf16, u);
}

// ws layout: bias_frag (6*64*64 f32 = 98304 B) | wbf (192*192 bf16 = 73728 B)
#define BIASF_FLOATS (HEADS*64*64)
#define WBF_OFF_B    (BIASF_FLOATS*4)

// ---------------- bias kernel: frag layout [h][row64][lrow16][4] ----------------
__global__ __launch_bounds__(128) void bias_kernel(
    const float* __restrict__ pos_w, const float* __restrict__ pos_scale,
    const float* __restrict__ meta_w1, const float* __restrict__ meta_b1,
    const float* __restrict__ meta_w2, const float* __restrict__ meta_b2,
    float* __restrict__ bias_frag)
{
    const int p = blockIdx.x;          // n*49+m
    const int n = p / NN, m = p % NN;
    const int i = threadIdx.x;         // 0..127
    __shared__ float hbuf[128];
    const float step = 2.0f / 6.0f;
    const float dx = (float)((n % WS) - (m % WS)) * step;
    const float dy = (float)((n / WS) - (m / WS)) * step;
    const float ps = pos_scale[0];
    float a = meta_b1[i];
    for (int d = 0; d < DIM; ++d) {
        float rel = ps * (pos_w[2*d] * dx + pos_w[2*d+1] * dy); // pos_b cancels
        a += rel * meta_w1[d*128 + i];
    }
    hbuf[i] = gelu_tanh(a);
    __syncthreads();
    if (i < HEADS) {
        float b = meta_b2[i];
        for (int j = 0; j < 128; ++j) b += hbuf[j] * meta_w2[j*HEADS + i];
        bias_frag[((i*64 + n)*16 + (m & 15))*4 + (m >> 4)] = b;
    }
}

// ---------------- prep: W -> bf16, zero bias_frag pad rows ----------------
__global__ __launch_bounds__(256) void prep_w(
    const float* __restrict__ proj_w, unsigned short* __restrict__ wbf,
    float* __restrict__ bias_frag)
{
    int idx = blockIdx.x*256 + threadIdx.x;
    if (idx < DIM*DIM) wbf[idx] = f2bf(proj_w[idx]);
    int z = idx - DIM*DIM;
    if (z >= 0 && z < HEADS*15*64) {
        int hh = z / 960, rem = z - hh*960;
        int row = 49 + (rem >> 6), inner = rem & 63;
        bias_frag[(hh*64 + row)*64 + inner] = 0.f;
    }
}

// LDS row strides (bf16 elems)
#define RSQ 40   // 80B rows
#define RSV 72   // 144B rows

// per-wave scratch float offsets (ca arrays first; 16B-aligned base)
#define S_CAQ 0
#define S_CAK 32
#define S_SM  64
#define S_MX  113
#define S_SAQ 162
#define S_SAK 211
#define S_SZ  272   // 1088 B per wave (16-mult)

// redundant per-wave PDSCA stats. PDSCA reshapes the flat 49x32 row-major
// buffer to (32 ch, 49 sp): flat j = n*32+d = c*49+sp. LDS addr of flat j:
// (j>>5)*RSQ + (j&31).
__device__ __forceinline__ void pdsca_stats(
    const unsigned short* raw,              // [49][RSQ] bf16
    const float* __restrict__ w1, const float* __restrict__ b1,
    const float* __restrict__ w2, const float* __restrict__ b2,
    const float* sw, float sab,             // conv weights (98 f in LDS), bias
    float* scr, float* caO, float* saO, int l)
{
    // channel mean over sp: 2 lanes per channel (sp split 25/24)
    int c = l & 31, h2 = l >> 5;
    int s0 = h2 ? 25 : 0, s1 = h2 ? 49 : 25;
    float s = 0.f;
    int j = c*NN + s0;
    for (int sp = s0; sp < s1; ++sp, ++j)
        s += bf2f(raw[(j >> 5)*RSQ + (j & 31)]);
    s += __shfl_xor(s, 32);
    float cm = s * (1.f/49.f);              // lane l holds cmean[l&31]
    // MLP hidden: o = l&7, partial over channels c2 = t8 + 8k, xor-tree reduce
    int o = l & 7, t8 = l >> 3;
    float part = 0.f;
    #pragma unroll
    for (int kk = 0; kk < 4; ++kk) {
        int c2 = t8 + (kk << 3);
        part += w1[(o << 5) + c2] * __shfl(cm, c2);
    }
    part += __shfl_xor(part, 8);
    part += __shfl_xor(part, 16);
    part += __shfl_xor(part, 32);
    float hid = gelu_tanh(part + b1[o]);    // lanes 0..7 hold hid[0..7]
    // channel out -> caO[c] (both halves write same value; benign)
    float a2 = b2[c];
    #pragma unroll
    for (int oo = 0; oo < 8; ++oo)
        a2 += w2[(c << 3) + oo] * __shfl(hid, oo);
    caO[c] = a2;
    // spatial mean/max over channels + 7x7 SAME conv (lane = sp)
    if (l < NN) {
        float sm = 0.f, mx = -1e30f;
        #pragma unroll
        for (int c2 = 0; c2 < HD; ++c2) {
            int j2 = c2*NN + l;
            float v = bf2f(raw[(j2 >> 5)*RSQ + (j2 & 31)]);
            sm += v; mx = fmaxf(mx, v);
        }
        scr[S_SM + l] = sm * (1.f/HD);
        scr[S_MX + l] = mx;
        int y = l / WS, x = l - y*WS;
        int y0 = max(0, y-3), y1 = min(6, y+3);
        int x0 = max(0, x-3), x1 = min(6, x+3);
        float a = sab;
        for (int iy = y0; iy <= y1; ++iy) {
            int ky = iy - y + 3;
            for (int ix = x0; ix <= x1; ++ix) {
                int kx = ix - x + 3;
                int s2 = iy*WS + ix;
                a += sw[ky*WS+kx] * scr[S_SM+s2] + sw[NN+ky*WS+kx] * scr[S_MX+s2];
            }
        }
        saO[l] = a;
    }
}

// read raw frag, apply sigmoid gate in registers: gate(x[n][d]) uses
// c = (n*32+d)/49, sp = (n*32+d)%49
__device__ __forceinline__ bf16x8_t gate_frag(
    const unsigned short* raw, int row, int lk8, const float* ca, const float* sa)
{
    bf16x8_t r = *(const bf16x8_t*)&raw[row*RSQ + lk8];
    bf16x8_t g;
    int flat = row*HD + lk8;
    #pragma unroll
    for (int e = 0; e < 8; ++e) {
        int f = flat + e;
        int c = f / NN, sp = f - c*NN;      // magic-mul div by 49
        float gg = 1.f / (1.f + __expf(-(ca[c] + sa[sp])));
        g[e] = (short)f2bf(bf2f((unsigned short)r[e]) * gg);
    }
    return g;
}

__global__ __launch_bounds__(256, 4) void win_attn_mfma(
    const float* __restrict__ qkv,
    const float* __restrict__ log_temp,
    const float* __restrict__ q_ca_w1, const float* __restrict__ q_ca_b1,
    const float* __restrict__ q_ca_w2, const float* __restrict__ q_ca_b2,
    const float* __restrict__ q_sa_w, const float* __restrict__ q_sa_b,
    const float* __restrict__ k_ca_w1, const float* __restrict__ k_ca_b1,
    const float* __restrict__ k_ca_w2, const float* __restrict__ k_ca_b2,
    const float* __restrict__ k_sa_w, const float* __restrict__ k_sa_b,
    const float* __restrict__ bias_frag,
    const unsigned short* __restrict__ wbf,
    float* __restrict__ out)
{
    __shared__ __align__(16) unsigned short q_raw[NN*RSQ];   // raw bf16 Q (dup-written)
    __shared__ __align__(16) unsigned short k_raw[NN*RSQ];
    __shared__ __align__(16) unsigned short v_t[32*RSV];     // V^T [d][m]
    __shared__ __align__(16) unsigned short p_st[4][16*RSV]; // per-wave P strip
    __shared__ __align__(16) unsigned short o_st[4][16*RSQ]; // per-wave O strip
    __shared__ __align__(16) float sw_s[2*98];               // q/k conv weights
    __shared__ __align__(16) float wsc_all[4*S_SZ];          // per-wave stats scratch

    const int t = threadIdx.x;
    const int b = blockIdx.x;
    const int l = t & 63;
    const int w = t >> 6;          // wave = row strip
    const int lrow = l & 15;
    const int lk = l >> 4;
    const int lk8 = lk * 8;
    float* wsc = wsc_all + w*S_SZ;
    unsigned short* p_w = p_st[w];
    unsigned short* o_w = o_st[w];
    const float temp = __expf(log_temp[0]);
    const float sabq = q_sa_b[0], sabk = k_sa_b[0];
    const float* qkv_b = qkv + (size_t)b * (NN*QKV_ROW);

    f32x4_t pacc[12];
    #pragma unroll
    for (int j = 0; j < 12; ++j) pacc[j] = (f32x4_t){0.f,0.f,0.f,0.f};

    // one-time per-wave (redundant, benign): conv weights + v_t pad cols 49..63
    for (int i = l; i < 2*98; i += 64) sw_s[i] = (i < 98) ? q_sa_w[i] : k_sa_w[i-98];
    for (int i = l; i < 32*15; i += 64) { int d = i/15, m = 49 + (i - d*15); v_t[d*RSV + m] = 0; }

    #pragma unroll 1
    for (int h = 0; h < HEADS; ++h) {
        // ---- redundant full-head staging (benign same-value races) ----
        for (int e = l; e < NN*8; e += 64) {
            int n = e >> 3, c = e & 7;
            const float* base = qkv_b + n*QKV_ROW + h*HD + (c<<2);
            float4 fq = *(const float4*)(base);
            float4 fk = *(const float4*)(base + DIM);
            float4 fv = *(const float4*)(base + 2*DIM);
            ushort4 uq = { f2bf(fq.x), f2bf(fq.y), f2bf(fq.z), f2bf(fq.w) };
            ushort4 uk = { f2bf(fk.x), f2bf(fk.y), f2bf(fk.z), f2bf(fk.w) };
            *(ushort4*)&q_raw[n*RSQ + (c<<2)] = uq;
            *(ushort4*)&k_raw[n*RSQ + (c<<2)] = uk;
            int d0 = c << 2;
            v_t[(d0+0)*RSV + n] = f2bf(fv.x);
            v_t[(d0+1)*RSV + n] = f2bf(fv.y);
            v_t[(d0+2)*RSV + n] = f2bf(fv.z);
            v_t[(d0+3)*RSV + n] = f2bf(fv.w);
        }
        // ---- redundant per-wave gate stats (correct c=j/49, sp=j%49 mapping) ----
        pdsca_stats(q_raw, q_ca_w1, q_ca_b1, q_ca_w2, q_ca_b2,
                    sw_s,      sabq, wsc, wsc + S_CAQ, wsc + S_SAQ, l);
        pdsca_stats(k_raw, k_ca_w1, k_ca_b1, k_ca_w2, k_ca_b2,
                    sw_s + 98, sabk, wsc, wsc + S_CAK, wsc + S_SAK, l);

        // ---- S = gated(Q_strip) gated(K)^T (gates applied in registers) ----
        int qrow = w*16 + lrow;
        int qc = qrow < NN ? qrow : NN-1;
        bf16x8_t aq = gate_frag(q_raw, qc, lk8, wsc + S_CAQ, wsc + S_SAQ);
        f32x4_t sac[4];
        #pragma unroll
        for (int j = 0; j < 4; ++j) {
            int mr = j*16 + lrow;
            int mc = mr < NN ? mr : NN-1;
            bf16x8_t bk = gate_frag(k_raw, mc, lk8, wsc + S_CAK, wsc + S_SAK);
            f32x4_t z = (f32x4_t){0.f,0.f,0.f,0.f};
            sac[j] = MFMA16(aq, bk, z);
        }

        // ---- softmax (bias in frag layout, one float4 per row) ----
        const float* bias_f = bias_frag + h*64*64;
        #pragma unroll
        for (int r = 0; r < 4; ++r) {
            int row = w*16 + lk*4 + r;
            float4 b4 = *(const float4*)(bias_f + (row*16 + lrow)*4);
            float v0 = sac[0][r]*temp + b4.x;
            float v1 = sac[1][r]*temp + b4.y;
            float v2 = sac[2][r]*temp + b4.z;
            float v3 = (lrow == 0) ? (sac[3][r]*temp + b4.w) : -1e30f;
            float mx = fmaxf(fmaxf(v0, v1), fmaxf(v2, v3));
            mx = fmaxf(mx, __shfl_xor(mx, 1));
            mx = fmaxf(mx, __shfl_xor(mx, 2));
            mx = fmaxf(mx, __shfl_xor(mx, 4));
            mx = fmaxf(mx, __shfl_xor(mx, 8));
            float e0 = __expf(v0 - mx), e1 = __expf(v1 - mx);
            float e2 = __expf(v2 - mx), e3 = __expf(v3 - mx);
            float sum = e0 + e1 + e2 + e3;
            sum += __shfl_xor(sum, 1);
            sum += __shfl_xor(sum, 2);
            sum += __shfl_xor(sum, 4);
            sum += __shfl_xor(sum, 8);
            float inv = 1.f / sum;
            int pb = (lk*4 + r)*RSV + lrow;
            p_w[pb +  0] = f2bf(e0 * inv);
            p_w[pb + 16] = f2bf(e1 * inv);
            p_w[pb + 32] = f2bf(e2 * inv);
            p_w[pb + 48] = f2bf(e3 * inv);
        }
        // same-wave LDS ordering: P write -> PV read needs no barrier

        // ---- O = P V ----
        f32x4_t oac[2];
        oac[0] = (f32x4_t){0.f,0.f,0.f,0.f};
        oac[1] = (f32x4_t){0.f,0.f,0.f,0.f};
        #pragma unroll
        for (int ks = 0; ks < 2; ++ks) {
            bf16x8_t ap = *(const bf16x8_t*)&p_w[lrow*RSV + ks*32 + lk8];
            #pragma unroll
            for (int nt = 0; nt < 2; ++nt) {
                bf16x8_t bv = *(const bf16x8_t*)&v_t[(nt*16 + lrow)*RSV + ks*32 + lk8];
                oac[nt] = MFMA16(ap, bv, oac[nt]);
            }
        }
        #pragma unroll
        for (int nt = 0; nt < 2; ++nt)
            #pragma unroll
            for (int r = 0; r < 4; ++r)
                o_w[(lk*4 + r)*RSQ + nt*16 + lrow] = f2bf(oac[nt][r]);

        __syncthreads();   // sole barrier: all shared reads of this head done

        // ---- projection partials (own o_w + L2-resident W) ----
        bf16x8_t ao = *(const bf16x8_t*)&o_w[lrow*RSQ + lk8];
        #pragma unroll
        for (int j = 0; j < 12; ++j) {
            bf16x8_t bwf = *(const bf16x8_t*)(wbf + (j*16 + lrow)*DIM + h*HD + lk8);
            pacc[j] = MFMA16(ao, bwf, pacc[j]);
        }
    }

    float* out_b = out + (size_t)b * (NN*DIM);
    #pragma unroll
    for (int j = 0; j < 12; ++j) {
        #pragma unroll
        for (int r = 0; r < 4; ++r) {
            int row = w*16 + lk*4 + r;
            if (row < NN)
                out_b[row*DIM + j*16 + lrow] = pacc[j][r];
        }
    }
}

extern "C" void kernel_launch(void* const* d_in, const int* in_sizes, int n_in,
                              void* d_out, int out_size, void* d_ws, size_t ws_size,
                              hipStream_t stream)
{
    (void)in_sizes; (void)n_in; (void)out_size; (void)ws_size;
    const float* qkv      = (const float*)d_in[0];
    const float* log_temp = (const float*)d_in[1];
    const float* pos_w    = (const float*)d_in[2];
    /* d_in[3] = pos_b cancels in pairwise diff */
    const float* pos_scale= (const float*)d_in[4];
    const float* meta_w1  = (const float*)d_in[5];
    const float* meta_b1  = (const float*)d_in[6];
    const float* meta_w2  = (const float*)d_in[7];
    const float* meta_b2  = (const float*)d_in[8];
    const float* q_ca_w1  = (const float*)d_in[9];
    const float* q_ca_b1  = (const float*)d_in[10];
    const float* q_ca_w2  = (const float*)d_in[11];
    const float* q_ca_b2  = (const float*)d_in[12];
    const float* q_sa_w   = (const float*)d_in[13];
    const float* q_sa_b   = (const float*)d_in[14];
    const float* k_ca_w1  = (const float*)d_in[15];
    const float* k_ca_b1  = (const float*)d_in[16];
    const float* k_ca_w2  = (const float*)d_in[17];
    const float* k_ca_b2  = (const float*)d_in[18];
    const float* k_sa_w   = (const float*)d_in[19];
    const float* k_sa_b   = (const float*)d_in[20];
    const float* proj_w   = (const float*)d_in[21];
    float* out = (float*)d_out;

    float* bias_frag = (float*)d_ws;
    unsigned short* wbf = (unsigned short*)((char*)d_ws + WBF_OFF_B);

    hipLaunchKernelGGL(bias_kernel, dim3(NN*NN), dim3(128), 0, stream,
                       pos_w, pos_scale, meta_w1, meta_b1, meta_w2, meta_b2, bias_frag);
    hipLaunchKernelGGL(prep_w, dim3((DIM*DIM + HEADS*15*64 + 255)/256), dim3(256), 0, stream,
                       proj_w, wbf, bias_frag);
    hipLaunchKernelGGL(win_attn_mfma, dim3(NWIN), dim3(256), 0, stream,
                       qkv, log_temp,
                       q_ca_w1, q_ca_b1, q_ca_w2, q_ca_b2, q_sa_w, q_sa_b,
                       k_ca_w1, k_ca_b1, k_ca_w2, k_ca_b2, k_sa_w, k_sa_b,
                       bias_frag, wbf, out);
}

// Round 7
// 637.957 us; speedup vs baseline: 2.5558x; 2.5558x over previous
//
#include <hip/hip_runtime.h>
#include <math.h>

#define DIM 192
#define HEADS 6
#define HD 32
#define WS 7
#define NN 49
#define NWIN 4096
#define QKV_ROW (3*DIM)

typedef __attribute__((ext_vector_type(8))) short bf16x8_t;
typedef __attribute__((ext_vector_type(4))) float f32x4_t;

#define MFMA16(a,b,c) __builtin_amdgcn_mfma_f32_16x16x32_bf16((a),(b),(c),0,0,0)

__device__ __forceinline__ float gelu_tanh(float x) {
    const float k0 = 0.7978845608028654f; // sqrt(2/pi)
    const float k1 = 0.044715f;
    float t = tanhf(k0 * (x + k1 * x * x * x));
    return 0.5f * x * (1.0f + t);
}
__device__ __forceinline__ unsigned short f2bf(float f) {
    __bf16 h = (__bf16)f;
    return __builtin_bit_cast(unsigned short, h);
}
__device__ __forceinline__ float bf2f(unsigned short u) {
    return (float)__builtin_bit_cast(__bf16, u);
}

// ws layout: bias_frag (6*64*64 f32 = 98304 B) | wbf (192*192 bf16 = 73728 B)
#define BIASF_FLOATS (HEADS*64*64)
#define WBF_OFF_B    (BIASF_FLOATS*4)

// ---------------- bias kernel: frag layout [h][row64][lrow16][4] ----------------
__global__ __launch_bounds__(128) void bias_kernel(
    const float* __restrict__ pos_w, const float* __restrict__ pos_scale,
    const float* __restrict__ meta_w1, const float* __restrict__ meta_b1,
    const float* __restrict__ meta_w2, const float* __restrict__ meta_b2,
    float* __restrict__ bias_frag)
{
    const int p = blockIdx.x;          // n*49+m
    const int n = p / NN, m = p % NN;
    const int i = threadIdx.x;         // 0..127
    __shared__ float hbuf[128];
    const float step = 2.0f / 6.0f;
    const float dx = (float)((n % WS) - (m % WS)) * step;
    const float dy = (float)((n / WS) - (m / WS)) * step;
    const float ps = pos_scale[0];
    float a = meta_b1[i];
    for (int d = 0; d < DIM; ++d) {
        float rel = ps * (pos_w[2*d] * dx + pos_w[2*d+1] * dy); // pos_b cancels
        a += rel * meta_w1[d*128 + i];
    }
    hbuf[i] = gelu_tanh(a);
    __syncthreads();
    if (i < HEADS) {
        float b = meta_b2[i];
        for (int j = 0; j < 128; ++j) b += hbuf[j] * meta_w2[j*HEADS + i];
        bias_frag[((i*64 + n)*16 + (m & 15))*4 + (m >> 4)] = b;
    }
}

// ---------------- prep: W -> bf16, zero bias_frag pad rows ----------------
__global__ __launch_bounds__(256) void prep_w(
    const float* __restrict__ proj_w, unsigned short* __restrict__ wbf,
    float* __restrict__ bias_frag)
{
    int idx = blockIdx.x*256 + threadIdx.x;
    if (idx < DIM*DIM) wbf[idx] = f2bf(proj_w[idx]);
    int z = idx - DIM*DIM;
    if (z >= 0 && z < HEADS*15*64) {
        int hh = z / 960, rem = z - hh*960;
        int row = 49 + (rem >> 6), inner = rem & 63;
        bias_frag[(hh*64 + row)*64 + inner] = 0.f;
    }
}

#define QS  200   // q_all/k_all row stride (192 + 8 pad): 400B rows, 2-way-max banks
#define RSV 72    // v_t / p row stride

// gate scratch (aliases the wave's p region; 179 floats <= 1152 ushorts)
#define G_SM 0
#define G_MX 49
#define G_CA 98
#define G_SA 130

// per-wave PDSCA gate for one tensor slice (head columns hoff..hoff+31 of xs).
// PDSCA reshape: flat j = n*32+d = c*49+sp; LDS elem addr (j>>5)*QS + hoff + (j&31).
__device__ __forceinline__ void gate_one(
    unsigned short* xs, int hoff,
    const float* __restrict__ w1, const float* __restrict__ b1,
    const float* __restrict__ w2, const float* __restrict__ b2,
    const float* sw, float sab, float* scr, int l)
{
    // channel mean: 2 lanes per channel (sp split 25/24)
    int c = l & 31, h2 = l >> 5;
    int s0 = h2 ? 25 : 0, s1 = h2 ? 49 : 25;
    float s = 0.f;
    for (int sp = s0; sp < s1; ++sp) {
        int j = c*NN + sp;
        s += bf2f(xs[(j >> 5)*QS + hoff + (j & 31)]);
    }
    s += __shfl_xor(s, 32);
    float cm = s * (1.f/49.f);              // all lanes: cmean[l&31]
    // MLP hidden: o = l&7, xor-tree over t8 groups
    int o = l & 7, t8 = l >> 3;
    float part = 0.f;
    #pragma unroll
    for (int kk = 0; kk < 4; ++kk) {
        int c2 = t8 + (kk << 3);
        part += w1[(o << 5) + c2] * __shfl(cm, c2);
    }
    part += __shfl_xor(part, 8);
    part += __shfl_xor(part, 16);
    part += __shfl_xor(part, 32);
    float hid = gelu_tanh(part + b1[o]);    // all lanes: hid[l&7]
    // channel-attention out -> scr[G_CA + c] (halves write identical values)
    float a2 = b2[c];
    #pragma unroll
    for (int oo = 0; oo < 8; ++oo)
        a2 += w2[(c << 3) + oo] * __shfl(hid, oo);
    scr[G_CA + c] = a2;
    // spatial mean/max + 7x7 SAME conv (lane = sp); same-wave LDS ordering
    if (l < NN) {
        float sm = 0.f, mx = -1e30f;
        #pragma unroll
        for (int c2 = 0; c2 < HD; ++c2) {
            int j2 = c2*NN + l;
            float v = bf2f(xs[(j2 >> 5)*QS + hoff + (j2 & 31)]);
            sm += v; mx = fmaxf(mx, v);
        }
        scr[G_SM + l] = sm * (1.f/HD);
        scr[G_MX + l] = mx;
    }
    if (l < NN) {
        int y = l / WS, x = l - y*WS;
        int y0 = max(0, y-3), y1 = min(6, y+3);
        int x0 = max(0, x-3), x1 = min(6, x+3);
        float a = sab;
        for (int iy = y0; iy <= y1; ++iy) {
            int ky = iy - y + 3;
            for (int ix = x0; ix <= x1; ++ix) {
                int kx = ix - x + 3;
                int s2 = iy*WS + ix;
                a += sw[ky*WS+kx] * scr[G_SM+s2] + sw[NN+ky*WS+kx] * scr[G_MX+s2];
            }
        }
        scr[G_SA + l] = a;
    }
    // write-back gated values (column-exclusive to this wave)
    for (int j = l; j < NN*HD; j += 64) {
        int c2 = j / NN, sp = j - c2*NN;
        int idx = (j >> 5)*QS + hoff + (j & 31);
        float g = 1.f / (1.f + __expf(-(scr[G_CA+c2] + scr[G_SA+sp])));
        xs[idx] = f2bf(bf2f(xs[idx]) * g);
    }
}

// 6 waves, wave w owns head w. Phase A barrier-free (exclusive regions);
// single __syncthreads(); cooperative projection with K=192 in-kernel.
__global__ __launch_bounds__(384) void win_attn_mfma(
    const float* __restrict__ qkv,
    const float* __restrict__ log_temp,
    const float* __restrict__ q_ca_w1, const float* __restrict__ q_ca_b1,
    const float* __restrict__ q_ca_w2, const float* __restrict__ q_ca_b2,
    const float* __restrict__ q_sa_w, const float* __restrict__ q_sa_b,
    const float* __restrict__ k_ca_w1, const float* __restrict__ k_ca_b1,
    const float* __restrict__ k_ca_w2, const float* __restrict__ k_ca_b2,
    const float* __restrict__ k_sa_w, const float* __restrict__ k_sa_b,
    const float* __restrict__ bias_frag,
    const unsigned short* __restrict__ wbf,
    float* __restrict__ out)
{
    __shared__ __align__(16) unsigned short q_all[NN*QS];       // gated Q -> O
    __shared__ __align__(16) unsigned short k_all[NN*QS];       // gated K
    __shared__ __align__(16) unsigned short v_t[DIM*RSV];       // V^T [d_glob][m]
    __shared__ __align__(16) unsigned short p_all[HEADS][16*RSV]; // P strip / gate scratch
    __shared__ __align__(16) float sw_s[196];                   // q|k conv weights

    const int t = threadIdx.x;
    const int b = blockIdx.x;
    const int w = t >> 6;          // wave = head
    const int l = t & 63;
    const int lrow = l & 15;
    const int lk = l >> 4;
    const int lk8 = lk * 8;
    const int hoff = w * HD;
    unsigned short* p_w = p_all[w];
    float* scr = (float*)p_w;      // gate scratch aliases p region (sequenced)
    const float temp = __expf(log_temp[0]);
    const float* qkv_b = qkv + (size_t)b * (NN*QKV_ROW);

    // every wave duplicate-writes sw (identical values; same-wave RAW ordering)
    for (int i = l; i < 196; i += 64)
        sw_s[i] = (i < 98) ? q_sa_w[i] : k_sa_w[i-98];
    // zero own v_t pad cols 49..71 (rows hoff..hoff+31 exclusive)
    for (int i = l; i < HD*23; i += 64) {
        int d = i / 23, m = 49 + (i - d*23);
        v_t[(hoff + d)*RSV + m] = 0;
    }
    // stage own head slice (fp32 -> bf16), exclusive columns/rows
    for (int e = l; e < NN*8; e += 64) {
        int n = e >> 3, c = e & 7;
        const float* base = qkv_b + n*QKV_ROW + hoff + (c<<2);
        float4 fq = *(const float4*)(base);
        float4 fk = *(const float4*)(base + DIM);
        float4 fv = *(const float4*)(base + 2*DIM);
        ushort4 uq = { f2bf(fq.x), f2bf(fq.y), f2bf(fq.z), f2bf(fq.w) };
        ushort4 uk = { f2bf(fk.x), f2bf(fk.y), f2bf(fk.z), f2bf(fk.w) };
        *(ushort4*)&q_all[n*QS + hoff + (c<<2)] = uq;
        *(ushort4*)&k_all[n*QS + hoff + (c<<2)] = uk;
        int d0 = c << 2;
        v_t[(hoff+d0+0)*RSV + n] = f2bf(fv.x);
        v_t[(hoff+d0+1)*RSV + n] = f2bf(fv.y);
        v_t[(hoff+d0+2)*RSV + n] = f2bf(fv.z);
        v_t[(hoff+d0+3)*RSV + n] = f2bf(fv.w);
    }

    // gates: stats + in-place write-back (raw reads precede write-back; q then k)
    gate_one(q_all, hoff, q_ca_w1, q_ca_b1, q_ca_w2, q_ca_b2, sw_s,      q_sa_b[0], scr, l);
    gate_one(k_all, hoff, k_ca_w1, k_ca_b1, k_ca_w2, k_ca_b2, sw_s + 98, k_sa_b[0], scr, l);

    // per-strip attention for own head
    const float* bias_f = bias_frag + w*64*64;
    #pragma unroll 1
    for (int s = 0; s < 4; ++s) {
        int ar = s*16 + lrow;
        int ac = ar < NN ? ar : NN-1;
        bf16x8_t aq = *(const bf16x8_t*)&q_all[ac*QS + hoff + lk8];
        f32x4_t sac[4];
        #pragma unroll
        for (int j = 0; j < 4; ++j) {
            int mr = j*16 + lrow;
            int mc = mr < NN ? mr : NN-1;
            bf16x8_t bk = *(const bf16x8_t*)&k_all[mc*QS + hoff + lk8];
            f32x4_t z = (f32x4_t){0.f,0.f,0.f,0.f};
            sac[j] = MFMA16(aq, bk, z);
        }
        #pragma unroll
        for (int r = 0; r < 4; ++r) {
            int row = s*16 + lk*4 + r;
            float4 b4 = *(const float4*)(bias_f + (row*16 + lrow)*4);
            float v0 = sac[0][r]*temp + b4.x;
            float v1 = sac[1][r]*temp + b4.y;
            float v2 = sac[2][r]*temp + b4.z;
            float v3 = (lrow == 0) ? (sac[3][r]*temp + b4.w) : -1e30f;
            float mx = fmaxf(fmaxf(v0, v1), fmaxf(v2, v3));
            mx = fmaxf(mx, __shfl_xor(mx, 1));
            mx = fmaxf(mx, __shfl_xor(mx, 2));
            mx = fmaxf(mx, __shfl_xor(mx, 4));
            mx = fmaxf(mx, __shfl_xor(mx, 8));
            float e0 = __expf(v0 - mx), e1 = __expf(v1 - mx);
            float e2 = __expf(v2 - mx), e3 = __expf(v3 - mx);
            float sum = e0 + e1 + e2 + e3;
            sum += __shfl_xor(sum, 1);
            sum += __shfl_xor(sum, 2);
            sum += __shfl_xor(sum, 4);
            sum += __shfl_xor(sum, 8);
            float inv = 1.f / sum;
            int pb = (lk*4 + r)*RSV + lrow;
            p_w[pb +  0] = f2bf(e0 * inv);
            p_w[pb + 16] = f2bf(e1 * inv);
            p_w[pb + 32] = f2bf(e2 * inv);
            p_w[pb + 48] = f2bf(e3 * inv);
        }
        // O = P V (same-wave LDS ordering)
        f32x4_t oac[2];
        oac[0] = (f32x4_t){0.f,0.f,0.f,0.f};
        oac[1] = (f32x4_t){0.f,0.f,0.f,0.f};
        #pragma unroll
        for (int ks = 0; ks < 2; ++ks) {
            bf16x8_t ap = *(const bf16x8_t*)&p_w[lrow*RSV + ks*32 + lk8];
            #pragma unroll
            for (int nt = 0; nt < 2; ++nt) {
                bf16x8_t bv = *(const bf16x8_t*)&v_t[(hoff + nt*16 + lrow)*RSV + ks*32 + lk8];
                oac[nt] = MFMA16(ap, bv, oac[nt]);
            }
        }
        // O overwrites own Q columns (strip's Q already consumed)
        #pragma unroll
        for (int nt = 0; nt < 2; ++nt)
            #pragma unroll
            for (int r = 0; r < 4; ++r) {
                int row = s*16 + lk*4 + r;
                if (row < NN)
                    q_all[row*QS + hoff + nt*16 + lrow] = f2bf(oac[nt][r]);
            }
    }

    __syncthreads();   // the only barrier: all heads' O visible

    // cooperative projection: out = O_cat(49x192) @ W^T, wave w -> f-tiles 2w,2w+1
    f32x4_t pacc[4][2];
    #pragma unroll
    for (int s2 = 0; s2 < 4; ++s2) {
        pacc[s2][0] = (f32x4_t){0.f,0.f,0.f,0.f};
        pacc[s2][1] = (f32x4_t){0.f,0.f,0.f,0.f};
    }
    #pragma unroll
    for (int s2 = 0; s2 < 4; ++s2) {
        int ar = s2*16 + lrow;
        int ac = ar < NN ? ar : NN-1;
        #pragma unroll
        for (int c = 0; c < 6; ++c) {
            bf16x8_t ao = *(const bf16x8_t*)&q_all[ac*QS + c*32 + lk8];
            #pragma unroll
            for (int jj = 0; jj < 2; ++jj) {
                bf16x8_t bw = *(const bf16x8_t*)(wbf + ((2*w+jj)*16 + lrow)*DIM + c*32 + lk8);
                pacc[s2][jj] = MFMA16(ao, bw, pacc[s2][jj]);
            }
        }
    }
    float* out_b = out + (size_t)b * (NN*DIM);
    #pragma unroll
    for (int s2 = 0; s2 < 4; ++s2)
        #pragma unroll
        for (int jj = 0; jj < 2; ++jj)
            #pragma unroll
            for (int r = 0; r < 4; ++r) {
                int row = s2*16 + lk*4 + r;
                if (row < NN)
                    out_b[row*DIM + (2*w+jj)*16 + lrow] = pacc[s2][jj][r];
            }
}

extern "C" void kernel_launch(void* const* d_in, const int* in_sizes, int n_in,
                              void* d_out, int out_size, void* d_ws, size_t ws_size,
                              hipStream_t stream)
{
    (void)in_sizes; (void)n_in; (void)out_size; (void)ws_size;
    const float* qkv      = (const float*)d_in[0];
    const float* log_temp = (const float*)d_in[1];
    const float* pos_w    = (const float*)d_in[2];
    /* d_in[3] = pos_b cancels in pairwise diff */
    const float* pos_scale= (const float*)d_in[4];
    const float* meta_w1  = (const float*)d_in[5];
    const float* meta_b1  = (const float*)d_in[6];
    const float* meta_w2  = (const float*)d_in[7];
    const float* meta_b2  = (const float*)d_in[8];
    const float* q_ca_w1  = (const float*)d_in[9];
    const float* q_ca_b1  = (const float*)d_in[10];
    const float* q_ca_w2  = (const float*)d_in[11];
    const float* q_ca_b2  = (const float*)d_in[12];
    const float* q_sa_w   = (const float*)d_in[13];
    const float* q_sa_b   = (const float*)d_in[14];
    const float* k_ca_w1  = (const float*)d_in[15];
    const float* k_ca_b1  = (const float*)d_in[16];
    const float* k_ca_w2  = (const float*)d_in[17];
    const float* k_ca_b2  = (const float*)d_in[18];
    const float* k_sa_w   = (const float*)d_in[19];
    const float* k_sa_b   = (const float*)d_in[20];
    const float* proj_w   = (const float*)d_in[21];
    float* out = (float*)d_out;

    float* bias_frag = (float*)d_ws;
    unsigned short* wbf = (unsigned short*)((char*)d_ws + WBF_OFF_B);

    hipLaunchKernelGGL(bias_kernel, dim3(NN*NN), dim3(128), 0, stream,
                       pos_w, pos_scale, meta_w1, meta_b1, meta_w2, meta_b2, bias_frag);
    hipLaunchKernelGGL(prep_w, dim3((DIM*DIM + HEADS*15*64 + 255)/256), dim3(256), 0, stream,
                       proj_w, wbf, bias_frag);
    hipLaunchKernelGGL(win_attn_mfma, dim3(NWIN), dim3(384), 0, stream,
                       qkv, log_temp,
                       q_ca_w1, q_ca_b1, q_ca_w2, q_ca_b2, q_sa_w, q_sa_b,
                       k_ca_w1, k_ca_b1, k_ca_w2, k_ca_b2, k_sa_w, k_sa_b,
                       bias_frag, wbf, out);
}

// Round 8
// 398.359 us; speedup vs baseline: 4.0929x; 1.6015x over previous
//
#include <hip/hip_runtime.h>
#include <math.h>

#define DIM 192
#define HEADS 6
#define HD 32
#define WS 7
#define NN 49
#define NWIN 4096
#define QKV_ROW (3*DIM)

typedef __attribute__((ext_vector_type(8))) short bf16x8_t;
typedef __attribute__((ext_vector_type(4))) float f32x4_t;

#define MFMA16(a,b,c) __builtin_amdgcn_mfma_f32_16x16x32_bf16((a),(b),(c),0,0,0)

__device__ __forceinline__ float gelu_tanh(float x) {
    const float k0 = 0.7978845608028654f; // sqrt(2/pi)
    const float k1 = 0.044715f;
    float t = tanhf(k0 * (x + k1 * x * x * x));
    return 0.5f * x * (1.0f + t);
}
__device__ __forceinline__ unsigned short f2bf(float f) {
    __bf16 h = (__bf16)f;
    return __builtin_bit_cast(unsigned short, h);
}
__device__ __forceinline__ float bf2f(unsigned short u) {
    return (float)__builtin_bit_cast(__bf16, u);
}

// ws layout: bias_frag (6*64*64 f32 = 98304 B) | wbf (192*192 bf16 = 73728 B)
#define BIASF_FLOATS (HEADS*64*64)
#define WBF_OFF_B    (BIASF_FLOATS*4)

// ---------------- bias kernel: frag layout [h][row64][lrow16][4] ----------------
__global__ __launch_bounds__(128) void bias_kernel(
    const float* __restrict__ pos_w, const float* __restrict__ pos_scale,
    const float* __restrict__ meta_w1, const float* __restrict__ meta_b1,
    const float* __restrict__ meta_w2, const float* __restrict__ meta_b2,
    float* __restrict__ bias_frag)
{
    const int p = blockIdx.x;          // n*49+m
    const int n = p / NN, m = p % NN;
    const int i = threadIdx.x;         // 0..127
    __shared__ float hbuf[128];
    const float step = 2.0f / 6.0f;
    const float dx = (float)((n % WS) - (m % WS)) * step;
    const float dy = (float)((n / WS) - (m / WS)) * step;
    const float ps = pos_scale[0];
    float a = meta_b1[i];
    for (int d = 0; d < DIM; ++d) {
        float rel = ps * (pos_w[2*d] * dx + pos_w[2*d+1] * dy); // pos_b cancels
        a += rel * meta_w1[d*128 + i];
    }
    hbuf[i] = gelu_tanh(a);
    __syncthreads();
    if (i < HEADS) {
        float b = meta_b2[i];
        for (int j = 0; j < 128; ++j) b += hbuf[j] * meta_w2[j*HEADS + i];
        bias_frag[((i*64 + n)*16 + (m & 15))*4 + (m >> 4)] = b;
    }
}

// ---------------- prep: W -> bf16, zero bias_frag pad rows ----------------
__global__ __launch_bounds__(256) void prep_w(
    const float* __restrict__ proj_w, unsigned short* __restrict__ wbf,
    float* __restrict__ bias_frag)
{
    int idx = blockIdx.x*256 + threadIdx.x;
    if (idx < DIM*DIM) wbf[idx] = f2bf(proj_w[idx]);
    int z = idx - DIM*DIM;
    if (z >= 0 && z < HEADS*15*64) {
        int hh = z / 960, rem = z - hh*960;
        int row = 49 + (rem >> 6), inner = rem & 63;
        bias_frag[(hh*64 + row)*64 + inner] = 0.f;
    }
}

#define QS  200   // q_all/k_all row stride (192 + 8 pad)
#define RSV 72    // p row stride

// gate scratch (aliases the wave's p region; 179 floats <= 2304 B)
#define G_SM 0
#define G_MX 49
#define G_CA 98
#define G_SA 130

// per-wave PDSCA gate for one tensor slice (head columns hoff..hoff+31 of xs).
// PDSCA reshape: flat j = n*32+d = c*49+sp; LDS elem addr (j>>5)*QS + hoff + (j&31).
__device__ __forceinline__ void gate_one(
    unsigned short* xs, int hoff,
    const float* __restrict__ w1, const float* __restrict__ b1,
    const float* __restrict__ w2, const float* __restrict__ b2,
    const float* sw, float sab, float* scr, int l)
{
    // channel mean: 2 lanes per channel (sp split 25/24)
    int c = l & 31, h2 = l >> 5;
    int s0 = h2 ? 25 : 0, s1 = h2 ? 49 : 25;
    float s = 0.f;
    for (int sp = s0; sp < s1; ++sp) {
        int j = c*NN + sp;
        s += bf2f(xs[(j >> 5)*QS + hoff + (j & 31)]);
    }
    s += __shfl_xor(s, 32);
    float cm = s * (1.f/49.f);              // all lanes: cmean[l&31]
    // MLP hidden: o = l&7, xor-tree over t8 groups
    int o = l & 7, t8 = l >> 3;
    float part = 0.f;
    #pragma unroll
    for (int kk = 0; kk < 4; ++kk) {
        int c2 = t8 + (kk << 3);
        part += w1[(o << 5) + c2] * __shfl(cm, c2);
    }
    part += __shfl_xor(part, 8);
    part += __shfl_xor(part, 16);
    part += __shfl_xor(part, 32);
    float hid = gelu_tanh(part + b1[o]);    // all lanes: hid[l&7]
    // channel-attention out -> scr[G_CA + c] (halves write identical values)
    float a2 = b2[c];
    #pragma unroll
    for (int oo = 0; oo < 8; ++oo)
        a2 += w2[(c << 3) + oo] * __shfl(hid, oo);
    scr[G_CA + c] = a2;
    // spatial mean/max + 7x7 SAME conv (lane = sp); same-wave LDS ordering
    if (l < NN) {
        float sm = 0.f, mx = -1e30f;
        #pragma unroll
        for (int c2 = 0; c2 < HD; ++c2) {
            int j2 = c2*NN + l;
            float v = bf2f(xs[(j2 >> 5)*QS + hoff + (j2 & 31)]);
            sm += v; mx = fmaxf(mx, v);
        }
        scr[G_SM + l] = sm * (1.f/HD);
        scr[G_MX + l] = mx;
        int y = l / WS, x = l - y*WS;
        int y0 = max(0, y-3), y1 = min(6, y+3);
        int x0 = max(0, x-3), x1 = min(6, x+3);
        float a = sab;
        for (int iy = y0; iy <= y1; ++iy) {
            int ky = iy - y + 3;
            for (int ix = x0; ix <= x1; ++ix) {
                int kx = ix - x + 3;
                int s2 = iy*WS + ix;
                a += sw[ky*WS+kx] * scr[G_SM+s2] + sw[NN+ky*WS+kx] * scr[G_MX+s2];
            }
        }
        scr[G_SA + l] = a;
    }
    // write-back gated values (column-exclusive to this wave)
    for (int j = l; j < NN*HD; j += 64) {
        int c2 = j / NN, sp = j - c2*NN;
        int idx = (j >> 5)*QS + hoff + (j & 31);
        float g = 1.f / (1.f + __expf(-(scr[G_CA+c2] + scr[G_SA+sp])));
        xs[idx] = f2bf(bf2f(xs[idx]) * g);
    }
}

// 6 waves, wave w owns head w. V^T lives in registers (16 VGPR/lane).
// Phase A barrier-free (exclusive regions); single __syncthreads();
// cooperative projection with K=192 in-kernel.
__global__ __launch_bounds__(384) void win_attn_mfma(
    const float* __restrict__ qkv,
    const float* __restrict__ log_temp,
    const float* __restrict__ q_ca_w1, const float* __restrict__ q_ca_b1,
    const float* __restrict__ q_ca_w2, const float* __restrict__ q_ca_b2,
    const float* __restrict__ q_sa_w, const float* __restrict__ q_sa_b,
    const float* __restrict__ k_ca_w1, const float* __restrict__ k_ca_b1,
    const float* __restrict__ k_ca_w2, const float* __restrict__ k_ca_b2,
    const float* __restrict__ k_sa_w, const float* __restrict__ k_sa_b,
    const float* __restrict__ bias_frag,
    const unsigned short* __restrict__ wbf,
    float* __restrict__ out)
{
    __shared__ __align__(16) unsigned short q_all[NN*QS];         // gated Q -> O
    __shared__ __align__(16) unsigned short k_all[NN*QS];         // gated K
    __shared__ __align__(16) unsigned short p_all[HEADS][16*RSV]; // P strip / gate scratch
    __shared__ __align__(16) float sw_s[196];                     // q|k conv weights

    const int t = threadIdx.x;
    const int b = blockIdx.x;
    const int w = t >> 6;          // wave = head
    const int l = t & 63;
    const int lrow = l & 15;
    const int lk = l >> 4;
    const int lk8 = lk * 8;
    const int hoff = w * HD;
    unsigned short* p_w = p_all[w];
    float* scr = (float*)p_w;      // gate scratch aliases p region (sequenced)
    const float temp = __expf(log_temp[0]);
    const float* qkv_b = qkv + (size_t)b * (NN*QKV_ROW);

    // every wave duplicate-writes sw (identical values; same-wave RAW ordering)
    for (int i = l; i < 196; i += 64)
        sw_s[i] = (i < 98) ? q_sa_w[i] : k_sa_w[i-98];

    // ---- V^T register frags, gathered directly from global (issued early;
    // latency hides under staging + gates). vfrag[ks][nt][e] = V[ks*32+lk8+e][nt*16+lrow]
    bf16x8_t vfrag[2][2];
    #pragma unroll
    for (int ks = 0; ks < 2; ++ks)
        #pragma unroll
        for (int nt = 0; nt < 2; ++nt) {
            bf16x8_t f;
            #pragma unroll
            for (int e = 0; e < 8; ++e) {
                int m = ks*32 + lk8 + e;
                float v = 0.f;
                if (m < NN)
                    v = qkv_b[(size_t)m*QKV_ROW + 2*DIM + hoff + nt*16 + lrow];
                f[e] = (short)f2bf(v);
            }
            vfrag[ks][nt] = f;
        }

    // stage own head's q,k slice (fp32 -> bf16), exclusive columns
    for (int e = l; e < NN*8; e += 64) {
        int n = e >> 3, c = e & 7;
        const float* base = qkv_b + n*QKV_ROW + hoff + (c<<2);
        float4 fq = *(const float4*)(base);
        float4 fk = *(const float4*)(base + DIM);
        ushort4 uq = { f2bf(fq.x), f2bf(fq.y), f2bf(fq.z), f2bf(fq.w) };
        ushort4 uk = { f2bf(fk.x), f2bf(fk.y), f2bf(fk.z), f2bf(fk.w) };
        *(ushort4*)&q_all[n*QS + hoff + (c<<2)] = uq;
        *(ushort4*)&k_all[n*QS + hoff + (c<<2)] = uk;
    }

    // gates: stats + in-place write-back (same-wave ordering; q then k)
    gate_one(q_all, hoff, q_ca_w1, q_ca_b1, q_ca_w2, q_ca_b2, sw_s,      q_sa_b[0], scr, l);
    gate_one(k_all, hoff, k_ca_w1, k_ca_b1, k_ca_w2, k_ca_b2, sw_s + 98, k_sa_b[0], scr, l);

    // per-strip attention for own head
    const float* bias_f = bias_frag + w*64*64;
    #pragma unroll 1
    for (int s = 0; s < 4; ++s) {
        int ar = s*16 + lrow;
        int ac = ar < NN ? ar : NN-1;
        bf16x8_t aq = *(const bf16x8_t*)&q_all[ac*QS + hoff + lk8];
        f32x4_t sac[4];
        #pragma unroll
        for (int j = 0; j < 4; ++j) {
            int mr = j*16 + lrow;
            int mc = mr < NN ? mr : NN-1;
            bf16x8_t bk = *(const bf16x8_t*)&k_all[mc*QS + hoff + lk8];
            f32x4_t z = (f32x4_t){0.f,0.f,0.f,0.f};
            sac[j] = MFMA16(aq, bk, z);
        }
        #pragma unroll
        for (int r = 0; r < 4; ++r) {
            int row = s*16 + lk*4 + r;
            float4 b4 = *(const float4*)(bias_f + (row*16 + lrow)*4);
            float v0 = sac[0][r]*temp + b4.x;
            float v1 = sac[1][r]*temp + b4.y;
            float v2 = sac[2][r]*temp + b4.z;
            float v3 = (lrow == 0) ? (sac[3][r]*temp + b4.w) : -1e30f;
            float mx = fmaxf(fmaxf(v0, v1), fmaxf(v2, v3));
            mx = fmaxf(mx, __shfl_xor(mx, 1));
            mx = fmaxf(mx, __shfl_xor(mx, 2));
            mx = fmaxf(mx, __shfl_xor(mx, 4));
            mx = fmaxf(mx, __shfl_xor(mx, 8));
            float e0 = __expf(v0 - mx), e1 = __expf(v1 - mx);
            float e2 = __expf(v2 - mx), e3 = __expf(v3 - mx);
            float sum = e0 + e1 + e2 + e3;
            sum += __shfl_xor(sum, 1);
            sum += __shfl_xor(sum, 2);
            sum += __shfl_xor(sum, 4);
            sum += __shfl_xor(sum, 8);
            float inv = 1.f / sum;
            int pb = (lk*4 + r)*RSV + lrow;
            p_w[pb +  0] = f2bf(e0 * inv);
            p_w[pb + 16] = f2bf(e1 * inv);
            p_w[pb + 32] = f2bf(e2 * inv);
            p_w[pb + 48] = f2bf(e3 * inv);
        }
        // O = P V (P from LDS same-wave; V^T from registers)
        f32x4_t oac[2];
        oac[0] = (f32x4_t){0.f,0.f,0.f,0.f};
        oac[1] = (f32x4_t){0.f,0.f,0.f,0.f};
        #pragma unroll
        for (int ks = 0; ks < 2; ++ks) {
            bf16x8_t ap = *(const bf16x8_t*)&p_w[lrow*RSV + ks*32 + lk8];
            #pragma unroll
            for (int nt = 0; nt < 2; ++nt)
                oac[nt] = MFMA16(ap, vfrag[ks][nt], oac[nt]);
        }
        // O overwrites own Q columns (strip's Q already consumed)
        #pragma unroll
        for (int nt = 0; nt < 2; ++nt)
            #pragma unroll
            for (int r = 0; r < 4; ++r) {
                int row = s*16 + lk*4 + r;
                if (row < NN)
                    q_all[row*QS + hoff + nt*16 + lrow] = f2bf(oac[nt][r]);
            }
    }

    __syncthreads();   // the only barrier: all heads' O visible

    // cooperative projection: out = O_cat(49x192) @ W^T, wave w -> f-tiles 2w,2w+1
    f32x4_t pacc[4][2];
    #pragma unroll
    for (int s2 = 0; s2 < 4; ++s2) {
        pacc[s2][0] = (f32x4_t){0.f,0.f,0.f,0.f};
        pacc[s2][1] = (f32x4_t){0.f,0.f,0.f,0.f};
    }
    #pragma unroll
    for (int s2 = 0; s2 < 4; ++s2) {
        int ar = s2*16 + lrow;
        int ac = ar < NN ? ar : NN-1;
        #pragma unroll
        for (int c = 0; c < 6; ++c) {
            bf16x8_t ao = *(const bf16x8_t*)&q_all[ac*QS + c*32 + lk8];
            #pragma unroll
            for (int jj = 0; jj < 2; ++jj) {
                bf16x8_t bw = *(const bf16x8_t*)(wbf + ((2*w+jj)*16 + lrow)*DIM + c*32 + lk8);
                pacc[s2][jj] = MFMA16(ao, bw, pacc[s2][jj]);
            }
        }
    }
    float* out_b = out + (size_t)b * (NN*DIM);
    #pragma unroll
    for (int s2 = 0; s2 < 4; ++s2)
        #pragma unroll
        for (int jj = 0; jj < 2; ++jj)
            #pragma unroll
            for (int r = 0; r < 4; ++r) {
                int row = s2*16 + lk*4 + r;
                if (row < NN)
                    out_b[row*DIM + (2*w+jj)*16 + lrow] = pacc[s2][jj][r];
            }
}

extern "C" void kernel_launch(void* const* d_in, const int* in_sizes, int n_in,
                              void* d_out, int out_size, void* d_ws, size_t ws_size,
                              hipStream_t stream)
{
    (void)in_sizes; (void)n_in; (void)out_size; (void)ws_size;
    const float* qkv      = (const float*)d_in[0];
    const float* log_temp = (const float*)d_in[1];
    const float* pos_w    = (const float*)d_in[2];
    /* d_in[3] = pos_b cancels in pairwise diff */
    const float* pos_scale= (const float*)d_in[4];
    const float* meta_w1  = (const float*)d_in[5];
    const float* meta_b1  = (const float*)d_in[6];
    const float* meta_w2  = (const float*)d_in[7];
    const float* meta_b2  = (const float*)d_in[8];
    const float* q_ca_w1  = (const float*)d_in[9];
    const float* q_ca_b1  = (const float*)d_in[10];
    const float* q_ca_w2  = (const float*)d_in[11];
    const float* q_ca_b2  = (const float*)d_in[12];
    const float* q_sa_w   = (const float*)d_in[13];
    const float* q_sa_b   = (const float*)d_in[14];
    const float* k_ca_w1  = (const float*)d_in[15];
    const float* k_ca_b1  = (const float*)d_in[16];
    const float* k_ca_w2  = (const float*)d_in[17];
    const float* k_ca_b2  = (const float*)d_in[18];
    const float* k_sa_w   = (const float*)d_in[19];
    const float* k_sa_b   = (const float*)d_in[20];
    const float* proj_w   = (const float*)d_in[21];
    float* out = (float*)d_out;

    float* bias_frag = (float*)d_ws;
    unsigned short* wbf = (unsigned short*)((char*)d_ws + WBF_OFF_B);

    hipLaunchKernelGGL(bias_kernel, dim3(NN*NN), dim3(128), 0, stream,
                       pos_w, pos_scale, meta_w1, meta_b1, meta_w2, meta_b2, bias_frag);
    hipLaunchKernelGGL(prep_w, dim3((DIM*DIM + HEADS*15*64 + 255)/256), dim3(256), 0, stream,
                       proj_w, wbf, bias_frag);
    hipLaunchKernelGGL(win_attn_mfma, dim3(NWIN), dim3(384), 0, stream,
                       qkv, log_temp,
                       q_ca_w1, q_ca_b1, q_ca_w2, q_ca_b2, q_sa_w, q_sa_b,
                       k_ca_w1, k_ca_b1, k_ca_w2, k_ca_b2, k_sa_w, k_sa_b,
                       bias_frag, wbf, out);
}